// Round 6
// baseline (2896.349 us; speedup 1.0000x reference)
//
#include <hip/hip_runtime.h>
#include <cstdint>
#include <cstddef>

// ---------------------------------------------------------------------------
// Sizes (fixed by the problem)
// ---------------------------------------------------------------------------
#define DIM    1024
#define NH     16
#define HD     64
#define DI     4
#define CHUNK_ 16
#define SEQ    4096
#define BATCH  4
#define NROWS  (BATCH * SEQ)       // 16384
#define NCHUNK (SEQ / CHUNK_)      // 256
#define SEG    64                  // conv in-place segment length (rows)
#define NSEG   (SEQ / SEG)         // 64

using bf16x8 = __attribute__((ext_vector_type(8))) short;
using f32x4  = __attribute__((ext_vector_type(4))) float;

typedef union { bf16x8 v; uint32_t u[4]; } B8;

__device__ __forceinline__ ushort f2bf(float f) {
    uint32_t u = __float_as_uint(f);
    u += 0x7FFFu + ((u >> 16) & 1u);      // RTNE
    return (ushort)(u >> 16);
}
__device__ __forceinline__ uint32_t pack2(float a, float b) {
    return (uint32_t)f2bf(a) | ((uint32_t)f2bf(b) << 16);
}
__device__ __forceinline__ float dot4(const float4 a, const float4 b) {
    return a.x*b.x + a.y*b.y + a.z*b.z + a.w*b.w;
}
__device__ __forceinline__ float redmax16(float x) {
    x = fmaxf(x, __shfl_xor(x, 1)); x = fmaxf(x, __shfl_xor(x, 2));
    x = fmaxf(x, __shfl_xor(x, 4)); x = fmaxf(x, __shfl_xor(x, 8));
    return x;
}
__device__ __forceinline__ float redsum16(float x) {
    x += __shfl_xor(x, 1); x += __shfl_xor(x, 2);
    x += __shfl_xor(x, 4); x += __shfl_xor(x, 8);
    return x;
}

// single-wave "barrier": compiler-only fence (no s_barrier, no vmcnt drain).
// HW DS ops retire in program order within a wave; sched_barrier(0) per guide
// rule #18 pins machine-level motion, asm clobber pins IR-level motion.
#define SYNC() do { asm volatile("" ::: "memory");          \
                    __builtin_amdgcn_wave_barrier();        \
                    __builtin_amdgcn_sched_barrier(0); } while (0)

// ---------------------------------------------------------------------------
// fp32 -> bf16 converter (grid-stride, 8 elems/thread)
// ---------------------------------------------------------------------------
__global__ __launch_bounds__(256)
void f2b_kernel(const float* __restrict__ in, ushort* __restrict__ out, int n8)
{
    int i = blockIdx.x * 256 + threadIdx.x;
    const int stride = gridDim.x * 256;
    for (; i < n8; i += stride) {
        float4 a = *(const float4*)&in[(size_t)i * 8];
        float4 b = *(const float4*)&in[(size_t)i * 8 + 4];
        uint4 u;
        u.x = pack2(a.x, a.y); u.y = pack2(a.z, a.w);
        u.z = pack2(b.x, b.y); u.w = pack2(b.z, b.w);
        *(uint4*)&out[(size_t)i * 8] = u;
    }
}

// ---------------------------------------------------------------------------
// bf16 MFMA GEMM (NT): verified primitives only (uint4 loads + ds_write +
// __syncthreads), bf16 inputs, BK=64, XOR slot^(row&7) swizzle both sides.
// C[m][n] = sum_k A[m*K+k]*B[n*K+k]; C fp32. 128x128 tile, 4 waves.
// ---------------------------------------------------------------------------
__global__ __launch_bounds__(256)
void gemm_nt_bf16w(const ushort* __restrict__ A, const ushort* __restrict__ B,
                   float* __restrict__ C, int K, int ldc)
{
    __shared__ ushort As[128][64];   // 16 KB
    __shared__ ushort Bs[128][64];

    const int tid  = threadIdx.x, wave = tid >> 6, lane = tid & 63;
    const int m0   = blockIdx.y * 128, n0 = blockIdx.x * 128;
    const int lo   = lane & 15, kg = lane >> 4;
    const int wm   = (wave >> 1) * 64, wn = (wave & 1) * 64;
    const int srow = tid >> 1, shalf = tid & 1;   // staging: row, k-half
    const int rs   = srow & 7;
    const int swz  = lo & 7;

    f32x4 acc[4][4];
#pragma unroll
    for (int i = 0; i < 4; ++i)
#pragma unroll
        for (int j = 0; j < 4; ++j) acc[i][j] = (f32x4){0.f, 0.f, 0.f, 0.f};

    const ushort* Ap = A + (size_t)(m0 + srow) * K + shalf * 32;
    const ushort* Bp = B + (size_t)(n0 + srow) * K + shalf * 32;

    for (int kt = 0; kt < K; kt += 64) {
        uint4 av[4], bv[4];
#pragma unroll
        for (int j = 0; j < 4; ++j) {
            av[j] = *(const uint4*)(Ap + kt + j * 8);
            bv[j] = *(const uint4*)(Bp + kt + j * 8);
        }
        __syncthreads();
#pragma unroll
        for (int j = 0; j < 4; ++j) {
            *(uint4*)&As[srow][((shalf * 4 + j) ^ rs) * 8] = av[j];
            *(uint4*)&Bs[srow][((shalf * 4 + j) ^ rs) * 8] = bv[j];
        }
        __syncthreads();

        bf16x8 af[2][4], bfr[2][4];
#pragma unroll
        for (int kk = 0; kk < 2; ++kk)
#pragma unroll
            for (int m = 0; m < 4; ++m) {
                const int s = (kk * 4 + kg) ^ swz;
                af[kk][m]  = *(const bf16x8*)&As[wm + m * 16 + lo][s * 8];
                bfr[kk][m] = *(const bf16x8*)&Bs[wn + m * 16 + lo][s * 8];
            }
#pragma unroll
        for (int kk = 0; kk < 2; ++kk)
#pragma unroll
            for (int mt = 0; mt < 4; ++mt)
#pragma unroll
                for (int nt = 0; nt < 4; ++nt)
                    acc[mt][nt] = __builtin_amdgcn_mfma_f32_16x16x32_bf16(
                        af[kk][mt], bfr[kk][nt], acc[mt][nt], 0, 0, 0);
    }

    const int col = lane & 15, r4 = (lane >> 4) * 4;
#pragma unroll
    for (int mt = 0; mt < 4; ++mt)
#pragma unroll
        for (int nt = 0; nt < 4; ++nt)
#pragma unroll
            for (int j = 0; j < 4; ++j)
                C[(size_t)(m0 + wm + mt * 16 + r4 + j) * ldc +
                  (n0 + wn + nt * 16 + col)] = acc[mt][nt][j];
}

// ---------------------------------------------------------------------------
// lr kernel (exact fp32): LR[r][o] = softplus(hs[r,:].Wlr[o,:] + 1e-3)
// ---------------------------------------------------------------------------
__global__ __launch_bounds__(256)
void lr_kernel(const float* __restrict__ hs, const float* __restrict__ Wlr,
               float* __restrict__ LR)
{
    __shared__ float row[DIM];
    const int r = blockIdx.x;
    const int t = threadIdx.x;
    *(float4*)&row[t * 4] = *(const float4*)&hs[(size_t)r * DIM + t * 4];
    __syncthreads();

    const int o = t >> 3;
    const int p = t & 7;
    const float* w = Wlr + (size_t)o * DIM + p * 128;
    const float* x = row + p * 128;
    float acc = 0.f;
#pragma unroll
    for (int i = 0; i < 32; ++i) {
        float4 xv = *(const float4*)(x + i * 4);
        float4 wv = *(const float4*)(w + i * 4);
        acc += dot4(xv, wv);
    }
    acc += __shfl_xor(acc, 1);
    acc += __shfl_xor(acc, 2);
    acc += __shfl_xor(acc, 4);
    if (p == 0) {
        float xx = acc + 0.001f;
        LR[(size_t)r * 32 + o] = (xx > 20.f) ? xx : log1pf(expf(xx));
    }
}

// ---------------------------------------------------------------------------
// halo save (unchanged)
// ---------------------------------------------------------------------------
__global__ __launch_bounds__(256)
void halo_save(const float* __restrict__ Q, const float* __restrict__ K,
               const float* __restrict__ V, float* __restrict__ HALO)
{
    int idx = blockIdx.x;
    int tn  = idx / (BATCH * (NSEG - 1) * 3);
    int rem = idx - tn * (BATCH * (NSEG - 1) * 3);
    int b   = rem / ((NSEG - 1) * 3);
    int rem2= rem - b * ((NSEG - 1) * 3);
    int s   = rem2 / 3 + 1;
    int j   = rem2 - (s - 1) * 3;

    const float* buf = (tn == 0) ? Q : ((tn == 1) ? K : V);
    size_t src = ((size_t)(b * SEQ + s * SEG - 3 + j)) * DIM + threadIdx.x * 4;
    size_t dst = ((size_t)((tn * BATCH + b) * NSEG + s) * 3 + j) * DIM + threadIdx.x * 4;
    *(float4*)&HALO[dst] = *(const float4*)&buf[src];
}

// ---------------------------------------------------------------------------
// conv in-place (unchanged)
// ---------------------------------------------------------------------------
__global__ __launch_bounds__(256)
void conv_inplace(float* __restrict__ Q, float* __restrict__ K,
                  float* __restrict__ V, const float* __restrict__ HALO,
                  const float* __restrict__ cq, const float* __restrict__ ck,
                  const float* __restrict__ cv)
{
    const int wid  = (blockIdx.x << 2) + (threadIdx.x >> 6);
    const int lane = threadIdx.x & 63;
    const int tn   = wid >> 12;
    const int rem  = wid & 4095;
    const int b    = rem >> 10;
    const int rem2 = rem & 1023;
    const int h    = rem2 >> 6;
    const int s    = rem2 & 63;
    const int c    = (h << 6) + lane;

    float* buf = (tn == 0) ? Q : ((tn == 1) ? K : V);
    const float* cw = (tn == 0) ? cq : ((tn == 1) ? ck : cv);
    float4 w4 = *(const float4*)(cw + (c << 2));

    float xm3 = 0.f, xm2 = 0.f, xm1 = 0.f;
    if (s > 0) {
        size_t hb = ((size_t)((tn * BATCH + b) * NSEG + s) * 3) * DIM + c;
        xm3 = HALO[hb];
        xm2 = HALO[hb + DIM];
        xm1 = HALO[hb + 2 * DIM];
    }

    size_t base = ((size_t)(b * SEQ + s * SEG)) * DIM + c;
    float x_next = buf[base];
#pragma unroll 4
    for (int i = 0; i < SEG; ++i) {
        float x = x_next;
        if (i < SEG - 1) x_next = buf[base + (size_t)(i + 1) * DIM];
        float y = xm3 * w4.x + xm2 * w4.y + xm1 * w4.z + x * w4.w + x;
        y = y / (1.f + __expf(-y));
        if (tn < 2) {
            float n2 = y * y;
#pragma unroll
            for (int m = 1; m < 64; m <<= 1) n2 += __shfl_xor(n2, m);
            y *= rsqrtf(n2);
        }
        buf[base + (size_t)i * DIM] = y;
        xm3 = xm2; xm2 = xm1; xm1 = x;
    }
}

// ---------------------------------------------------------------------------
// MFMA scan, barrier-free single wave per (b,h) chain (round-4 math, with
// max-subtraction restored in the inner softmax). bf16 output.
// ---------------------------------------------------------------------------
__global__ __launch_bounds__(64)
void scan_kernel(const float* QP, const float* __restrict__ KP,
                 const float* __restrict__ VP, const float* __restrict__ LRb,
                 const float* __restrict__ GATE,
                 const float* __restrict__ Wi0, const float* __restrict__ Wo0,
                 const float* __restrict__ lng, const float* __restrict__ lnb,
                 ushort* OB)
{
    const int bh = blockIdx.x, b = bh >> 4, h = bh & 15;
    const int t  = threadIdx.x, lo = t & 15, g = t >> 4;

    __shared__ ushort KA[16][72], QA[16][72], VA[16][72];   // rows [l][d]
    __shared__ ushort KT[64][24];                           // K^T [d][l]
    __shared__ ushort VT[64][40];                           // [d][V^T | Wo^T | 0]
    __shared__ ushort WiA[16][72], WoA[16][72];             // [D][d], rows 4+ zero
    __shared__ ushort QKT[16][32];                          // [q][qk | q_h | 0]
    __shared__ ushort P0s[16][32], P1s[16][32], KH[16][32];
    __shared__ float  sG[16][68];

    for (int i = t; i < 16 * 72; i += 64) { ((ushort*)WiA)[i] = 0; ((ushort*)WoA)[i] = 0; }
    for (int i = t; i < 64 * 24; i += 64) ((ushort*)KT)[i] = 0;
    for (int i = t; i < 64 * 40; i += 64) ((ushort*)VT)[i] = 0;
    for (int i = t; i < 16 * 32; i += 64) {
        ((ushort*)QKT)[i] = 0; ((ushort*)P0s)[i] = 0;
        ((ushort*)P1s)[i] = 0; ((ushort*)KH)[i]  = 0;
    }

    f32x4 wiC[4], woC[4];
#pragma unroll
    for (int n = 0; n < 4; ++n) { wiC[n] = (f32x4){0,0,0,0}; woC[n] = (f32x4){0,0,0,0}; }
    if (g == 0) {
#pragma unroll
        for (int n = 0; n < 4; ++n)
#pragma unroll
            for (int D = 0; D < 4; ++D) {
                float wi = Wi0[((size_t)D * NH + h) * HD + 16 * n + lo];
                float wo = Wo0[((size_t)D * NH + h) * HD + 16 * n + lo];
                wiC[n][D] = wi; woC[n][D] = wo;
                WiA[D][16 * n + lo] = f2bf(wi);
                WoA[D][16 * n + lo] = f2bf(wo);
                VT[16 * n + lo][16 + D] = f2bf(wo);
            }
    }
    SYNC();

    float lnGr[4], lnBr[4];
#pragma unroll
    for (int n = 0; n < 4; ++n) { lnGr[n] = lng[16 * n + lo]; lnBr[n] = lnb[16 * n + lo]; }

    const int rowb = b * SEQ;
    float4 pq[4], pk[4], pv[4], pg[4];
    float plr = 0.f;
    {
#pragma unroll
        for (int i = 0; i < 4; ++i) {
            size_t go = (size_t)(rowb + i * 4 + g) * DIM + h * 64 + 4 * lo;
            pq[i] = *(const float4*)&QP[go];
            pk[i] = *(const float4*)&KP[go];
            pv[i] = *(const float4*)&VP[go];
            pg[i] = *(const float4*)&GATE[go];
        }
        if (t < 32) plr = LRb[(size_t)(rowb + (t >> 1)) * 32 + h * 2 + (t & 1)];
    }

    const f32x4 z4 = (f32x4){0.f, 0.f, 0.f, 0.f};

    for (int c = 0; c < NCHUNK; ++c) {
        const int rb = rowb + c * CHUNK_;

        // ---- stage chunk (regs -> LDS, bf16 + transposed copies) ----
#pragma unroll
        for (int i = 0; i < 4; ++i) {
            const int row = i * 4 + g;
            *(float4*)&sG[row][4 * lo] = pg[i];
            uint2 uq; uq.x = pack2(pq[i].x, pq[i].y); uq.y = pack2(pq[i].z, pq[i].w);
            *(uint2*)&QA[row][4 * lo] = uq;
            uint2 uk; uk.x = pack2(pk[i].x, pk[i].y); uk.y = pack2(pk[i].z, pk[i].w);
            *(uint2*)&KA[row][4 * lo] = uk;
            uint2 uv; uv.x = pack2(pv[i].x, pv[i].y); uv.y = pack2(pv[i].z, pv[i].w);
            *(uint2*)&VA[row][4 * lo] = uv;
            KT[4 * lo + 0][row] = (ushort)(uk.x & 0xFFFF);
            KT[4 * lo + 1][row] = (ushort)(uk.x >> 16);
            KT[4 * lo + 2][row] = (ushort)(uk.y & 0xFFFF);
            KT[4 * lo + 3][row] = (ushort)(uk.y >> 16);
            VT[4 * lo + 0][row] = (ushort)(uv.x & 0xFFFF);
            VT[4 * lo + 1][row] = (ushort)(uv.x >> 16);
            VT[4 * lo + 2][row] = (ushort)(uv.y & 0xFFFF);
            VT[4 * lo + 3][row] = (ushort)(uv.y >> 16);
        }
        const float lr1    = __shfl(plr, 2 * lo + 1);
        const float lr_in  = __shfl(plr, 0);
        const float lr_out = __shfl(plr, 1);

        // ---- prefetch next chunk (floats across the whole chunk) ----
        if (c + 1 < NCHUNK) {
            const int rb2 = rb + CHUNK_;
#pragma unroll
            for (int i = 0; i < 4; ++i) {
                size_t go = (size_t)(rb2 + i * 4 + g) * DIM + h * 64 + 4 * lo;
                pq[i] = *(const float4*)&QP[go];
                pk[i] = *(const float4*)&KP[go];
                pv[i] = *(const float4*)&VP[go];
                pg[i] = *(const float4*)&GATE[go];
            }
            if (t < 32) plr = LRb[(size_t)(rb2 + (t >> 1)) * 32 + h * 2 + (t & 1)];
        }
        SYNC();

        // ---- M1/M2: logits^T  cK[D][l], cQ[D][l] (valid lanes 0-15) ----
        bf16x8 xWi0 = *(const bf16x8*)&WiA[lo][g * 8];
        bf16x8 xWi1 = *(const bf16x8*)&WiA[lo][g * 8 + 32];
        f32x4 cK = __builtin_amdgcn_mfma_f32_16x16x32_bf16(
            xWi0, *(const bf16x8*)&KA[lo][g * 8], z4, 0, 0, 0);
        cK = __builtin_amdgcn_mfma_f32_16x16x32_bf16(
            xWi1, *(const bf16x8*)&KA[lo][g * 8 + 32], cK, 0, 0, 0);
        f32x4 cQ = __builtin_amdgcn_mfma_f32_16x16x32_bf16(
            xWi0, *(const bf16x8*)&QA[lo][g * 8], z4, 0, 0, 0);
        cQ = __builtin_amdgcn_mfma_f32_16x16x32_bf16(
            xWi1, *(const bf16x8*)&QA[lo][g * 8 + 32], cQ, 0, 0, 0);

        // ---- softmax over D: register-local ----
        float mK = fmaxf(fmaxf(cK[0], cK[1]), fmaxf(cK[2], cK[3]));
        float ek0 = __expf(cK[0] - mK), ek1 = __expf(cK[1] - mK);
        float ek2 = __expf(cK[2] - mK), ek3 = __expf(cK[3] - mK);
        float ivk = lr1 / (ek0 + ek1 + ek2 + ek3);
        float kh0 = ek0 * ivk, kh1 = ek1 * ivk, kh2 = ek2 * ivk, kh3 = ek3 * ivk;

        float mQ = fmaxf(fmaxf(cQ[0], cQ[1]), fmaxf(cQ[2], cQ[3]));
        float eq0 = __expf(cQ[0] - mQ), eq1 = __expf(cQ[1] - mQ);
        float eq2 = __expf(cQ[2] - mQ), eq3 = __expf(cQ[3] - mQ);
        float ivq = 1.f / (eq0 + eq1 + eq2 + eq3);
        float qh0 = eq0 * ivq, qh1 = eq1 * ivq, qh2 = eq2 * ivq, qh3 = eq3 * ivq;

        // ---- M3: qk = q_h @ k_h^T (pure-register) ----
        B8 aQh, bKh;
        aQh.u[0] = aQh.u[1] = aQh.u[2] = aQh.u[3] = 0;
        bKh.u[0] = bKh.u[1] = bKh.u[2] = bKh.u[3] = 0;
        if (g == 0) {
            aQh.u[0] = pack2(qh0, qh1); aQh.u[1] = pack2(qh2, qh3);
            bKh.u[0] = pack2(kh0, kh1); bKh.u[1] = pack2(kh2, kh3);
        }
        f32x4 cQK = __builtin_amdgcn_mfma_f32_16x16x32_bf16(aQh.v, bKh.v, z4, 0, 0, 0);

        // ---- bounce qk (tril) + q_h into QKT ----
#pragma unroll
        for (int r = 0; r < 4; ++r) {
            const int q = 4 * g + r;
            QKT[q][lo] = (lo <= q) ? f2bf(cQK[r]) : (ushort)0;
        }
        if (g == 0) {
            QKT[lo][16] = f2bf(qh0); QKT[lo][17] = f2bf(qh1);
            QKT[lo][18] = f2bf(qh2); QKT[lo][19] = f2bf(qh3);
        }
        SYNC();

        // ---- M4: o = qk_ext @ [V | Wo] ----
        bf16x8 aO = *(const bf16x8*)&QKT[lo][g * 8];
        f32x4 oA[4];
#pragma unroll
        for (int n = 0; n < 4; ++n)
            oA[n] = __builtin_amdgcn_mfma_f32_16x16x32_bf16(
                aO, *(const bf16x8*)&VT[16 * n + lo][g * 8], z4, 0, 0, 0);

        // ---- LN + gate + bf16 store ----
#pragma unroll
        for (int r = 0; r < 4; ++r) {
            float s1 = oA[0][r] + oA[1][r] + oA[2][r] + oA[3][r];
            float s2 = oA[0][r] * oA[0][r] + oA[1][r] * oA[1][r] +
                       oA[2][r] * oA[2][r] + oA[3][r] * oA[3][r];
            s1 = redsum16(s1); s2 = redsum16(s2);
            float mu = s1 * (1.f / 64.f);
            float rstd = rsqrtf(s2 * (1.f / 64.f) - mu * mu + 1e-5f);
            const int q = 4 * g + r;
#pragma unroll
            for (int n = 0; n < 4; ++n) {
                float val = (oA[n][r] - mu) * rstd * lnGr[n] + lnBr[n];
                val *= sG[q][16 * n + lo];
                OB[(size_t)(rb + q) * DIM + h * 64 + 16 * n + lo] = f2bf(val);
            }
        }

        // ---- update1: W_out += k_h^T @ V ----
        if (g == 0) {
            KH[0][lo] = f2bf(kh0); KH[1][lo] = f2bf(kh1);
            KH[2][lo] = f2bf(kh2); KH[3][lo] = f2bf(kh3);
        }
        SYNC();
        {
            bf16x8 aKH = *(const bf16x8*)&KH[lo][g * 8];
#pragma unroll
            for (int n = 0; n < 4; ++n)
                woC[n] = __builtin_amdgcn_mfma_f32_16x16x32_bf16(
                    aKH, *(const bf16x8*)&VT[16 * n + lo][g * 8], woC[n], 0, 0, 0);
        }
        if (g == 0) {
#pragma unroll
            for (int n = 0; n < 4; ++n)
#pragma unroll
                for (int D = 0; D < 4; ++D)
                    WoA[D][16 * n + lo] = f2bf(woC[n][D]);
        }
        SYNC();

        // ---- inner TTT loop (2 iters) ----
#pragma unroll
        for (int it = 0; it < 2; ++it) {
            f32x4 s0v;
            if (it == 0) {
                s0v = cK;                      // logits reuse (Wi unchanged)
            } else {
                bf16x8 yWi0 = *(const bf16x8*)&WiA[lo][g * 8];
                bf16x8 yWi1 = *(const bf16x8*)&WiA[lo][g * 8 + 32];
                s0v = __builtin_amdgcn_mfma_f32_16x16x32_bf16(
                    yWi0, *(const bf16x8*)&KA[lo][g * 8], z4, 0, 0, 0);
                s0v = __builtin_amdgcn_mfma_f32_16x16x32_bf16(
                    yWi1, *(const bf16x8*)&KA[lo][g * 8 + 32], s0v, 0, 0, 0);
            }
            bf16x8 yWo0 = *(const bf16x8*)&WoA[lo][g * 8];
            bf16x8 yWo1 = *(const bf16x8*)&WoA[lo][g * 8 + 32];
            f32x4 s1v = __builtin_amdgcn_mfma_f32_16x16x32_bf16(
                yWo0, *(const bf16x8*)&VA[lo][g * 8], z4, 0, 0, 0);
            s1v = __builtin_amdgcn_mfma_f32_16x16x32_bf16(
                yWo1, *(const bf16x8*)&VA[lo][g * 8 + 32], s1v, 0, 0, 0);

            // softmax over j (16 lanes), max-subtracted
            float p0v[4], p1v[4];
#pragma unroll
            for (int r = 0; r < 4; ++r) {
                float x0 = s0v[r] * 0.125f, x1 = s1v[r] * 0.125f;
                float m0v = redmax16(x0), m1v = redmax16(x1);
                float e0 = __expf(x0 - m0v), e1 = __expf(x1 - m1v);
                p0v[r] = e0 / redsum16(e0);
                p1v[r] = e1 / redsum16(e1);
            }
            if (g == 0) {
#pragma unroll
                for (int r = 0; r < 4; ++r) {
                    P0s[r][lo] = f2bf(p0v[r] * lr_out);
                    P1s[r][lo] = f2bf(p1v[r] * lr_in);
                }
            }
            SYNC();

            bf16x8 aP0 = *(const bf16x8*)&P0s[lo][g * 8];
            bf16x8 aP1 = *(const bf16x8*)&P1s[lo][g * 8];
#pragma unroll
            for (int n = 0; n < 4; ++n) {
                woC[n] = __builtin_amdgcn_mfma_f32_16x16x32_bf16(
                    aP0, *(const bf16x8*)&VT[16 * n + lo][g * 8], woC[n], 0, 0, 0);
                wiC[n] = __builtin_amdgcn_mfma_f32_16x16x32_bf16(
                    aP1, *(const bf16x8*)&KT[16 * n + lo][g * 8], wiC[n], 0, 0, 0);
            }
            if (g == 0) {
#pragma unroll
                for (int n = 0; n < 4; ++n)
#pragma unroll
                    for (int D = 0; D < 4; ++D) {
                        WiA[D][16 * n + lo] = f2bf(wiC[n][D]);
                        WoA[D][16 * n + lo] = f2bf(woC[n][D]);
                        if (it == 1) VT[16 * n + lo][16 + D] = f2bf(woC[n][D]);
                    }
            }
            SYNC();
        }
    }
}

// ---------------------------------------------------------------------------
// launch
// ---------------------------------------------------------------------------
extern "C" void kernel_launch(void* const* d_in, const int* in_sizes, int n_in,
                              void* d_out, int out_size, void* d_ws, size_t ws_size,
                              hipStream_t stream)
{
    const float* hs  = (const float*)d_in[0];
    const float* Wq  = (const float*)d_in[1];
    const float* Wk  = (const float*)d_in[2];
    const float* Wv  = (const float*)d_in[3];
    const float* Wlr = (const float*)d_in[4];
    const float* Wg  = (const float*)d_in[5];
    const float* Wo  = (const float*)d_in[6];
    const float* cq  = (const float*)d_in[7];
    const float* ck  = (const float*)d_in[8];
    const float* cv  = (const float*)d_in[9];
    const float* Wi0 = (const float*)d_in[10];
    const float* Wo0 = (const float*)d_in[11];
    const float* lng = (const float*)d_in[12];
    const float* lnb = (const float*)d_in[13];

    // ws layout (~245 MB): Qf,Kf,Vf fp32 | LR | HALO | hsb bf16 (->OBUF) | Wb[5]
    float* ws   = (float*)d_ws;
    float* Qf   = ws;
    float* Kf   = Qf + (size_t)NROWS * DIM;
    float* Vf   = Kf + (size_t)NROWS * DIM;
    float* LRb  = Vf + (size_t)NROWS * DIM;
    float* HALO = LRb + (size_t)NROWS * 32;
    ushort* hsb = (ushort*)(HALO + (size_t)3 * BATCH * NSEG * 3 * DIM);
    ushort* Wqb = hsb + (size_t)NROWS * DIM;
    ushort* Wkb = Wqb + (size_t)DIM * DIM;
    ushort* Wvb = Wkb + (size_t)DIM * DIM;
    ushort* Wgb = Wvb + (size_t)DIM * DIM;
    ushort* Wob = Wgb + (size_t)DIM * DIM;
    float*  GATE = (float*)d_out;
    ushort* OBUF = hsb;     // hsb dead after projection GEMMs (stream-ordered)

    dim3 blk(256);

    // fp32 -> bf16 conversions
    f2b_kernel<<<2048, blk, 0, stream>>>(hs, hsb, NROWS * DIM / 8);
    f2b_kernel<<<512, blk, 0, stream>>>(Wq, Wqb, DIM * DIM / 8);
    f2b_kernel<<<512, blk, 0, stream>>>(Wk, Wkb, DIM * DIM / 8);
    f2b_kernel<<<512, blk, 0, stream>>>(Wv, Wvb, DIM * DIM / 8);
    f2b_kernel<<<512, blk, 0, stream>>>(Wg, Wgb, DIM * DIM / 8);
    f2b_kernel<<<512, blk, 0, stream>>>(Wo, Wob, DIM * DIM / 8);

    // projections (bf16 in, fp32 out)
    gemm_nt_bf16w<<<dim3(8, 128), blk, 0, stream>>>(hsb, Wqb, Qf,   1024, DIM);
    gemm_nt_bf16w<<<dim3(8, 128), blk, 0, stream>>>(hsb, Wkb, Kf,   1024, DIM);
    gemm_nt_bf16w<<<dim3(8, 128), blk, 0, stream>>>(hsb, Wvb, Vf,   1024, DIM);
    gemm_nt_bf16w<<<dim3(8, 128), blk, 0, stream>>>(hsb, Wgb, GATE, 1024, DIM);

    lr_kernel<<<NROWS, blk, 0, stream>>>(hs, Wlr, LRb);

    halo_save<<<3 * BATCH * (NSEG - 1) * 3, blk, 0, stream>>>(Qf, Kf, Vf, HALO);
    conv_inplace<<<(3 * BATCH * NH * NSEG) / 4, blk, 0, stream>>>(Qf, Kf, Vf, HALO,
                                                                  cq, ck, cv);

    scan_kernel<<<BATCH * NH, dim3(64), 0, stream>>>(Qf, Kf, Vf, LRb, GATE,
                                                     Wi0, Wo0, lng, lnb, OBUF);

    // out = (o_ln * gate) @ Wo^T
    gemm_nt_bf16w<<<dim3(8, 128), blk, 0, stream>>>(OBUF, Wob, (float*)d_out,
                                                    1024, 1024);
}